// Round 4
// baseline (36007.755 us; speedup 1.0000x reference)
//
#include <hip/hip_runtime.h>
#include <cstdint>
#include <cstddef>

#define LSEQ 512
#define NBATCH 256
#define INP 6
#define NBLK 192

typedef _Float16 f16;
typedef f16 f16x8 __attribute__((ext_vector_type(8)));
typedef float f32x4 __attribute__((ext_vector_type(4)));

static __device__ __forceinline__ float sigm(float x){ return 1.f/(1.f+__expf(-x)); }
static __device__ __forceinline__ float tanh_f(float x){
    x = fminf(fmaxf(x,-15.f),15.f);
    float t = __expf(-2.f*x);
    return (1.f-t)/(1.f+t);
}

// Manual grid barrier: bar[0]=arrive count, bar[1]=generation. All NBLK blocks
// are co-resident by construction (192 blocks, 1/CU, persistent) so spinning
// is deadlock-free. Writer: threadfence (device-scope WB) before arrive-add;
// reader: acquire on generation + fence.
static __device__ __forceinline__ void grid_barrier(int* bar){
    __syncthreads();
    if (threadIdx.x == 0){
        __threadfence();
        int g = __hip_atomic_load(&bar[1], __ATOMIC_RELAXED, __HIP_MEMORY_SCOPE_AGENT);
        int old = __hip_atomic_fetch_add(&bar[0], 1, __ATOMIC_ACQ_REL, __HIP_MEMORY_SCOPE_AGENT);
        if (old == NBLK - 1){
            __hip_atomic_store(&bar[0], 0, __ATOMIC_RELAXED, __HIP_MEMORY_SCOPE_AGENT);
            __hip_atomic_store(&bar[1], g + 1, __ATOMIC_RELEASE, __HIP_MEMORY_SCOPE_AGENT);
        } else {
            while (__hip_atomic_load(&bar[1], __ATOMIC_ACQUIRE, __HIP_MEMORY_SCOPE_AGENT) == g){
                __builtin_amdgcn_s_sleep(8);
            }
        }
        __threadfence();
    }
    __syncthreads();
}

// ---------------- weight packing (once per call) ----------------
// B0: [nb 64][kc 128][r 64][8], r = g*16+jl, row = g*1024 + nb*16 + jl, k = kc*8+jj
__global__ void pack_B0(const float* __restrict__ Whh0, f16* __restrict__ B0){
    int flat = blockIdx.x*256 + threadIdx.x;          // 524288
    int r = flat & 63, kc = (flat>>6)&127, nb = flat>>13;
    int g = r>>4, jl = r&15;
    const float* s = Whh0 + (size_t)(g*1024 + nb*16 + jl)*1024 + kc*8;
    float4 a = *(const float4*)s, b = *(const float4*)(s+4);
    f16x8 v = {(f16)a.x,(f16)a.y,(f16)a.z,(f16)a.w,(f16)b.x,(f16)b.y,(f16)b.z,(f16)b.w};
    *(f16x8*)(B0 + (size_t)flat*8) = v;
}
// B1: [nb 32][kc 256][r 128][8], r = w*32+tt*16+sub, gate=tt*2+(sub>>3), j=nb*32+w*8+(sub&7)
__global__ void pack_B1(const float* __restrict__ Wih1, const float* __restrict__ Whh1,
                        f16* __restrict__ B1){
    int flat = blockIdx.x*256 + threadIdx.x;          // 1048576
    int r = flat & 127, kc = (flat>>7)&255, nb = flat>>15;
    int w = r>>5, tt = (r>>4)&1, sub = r&15;
    int gate = tt*2 + (sub>>3);
    int j = nb*32 + w*8 + (sub&7);
    int R = gate*1024 + j;
    int k = kc*8;
    const float* s = (k<1024) ? (Wih1 + (size_t)R*1024 + k)
                              : (Whh1 + (size_t)R*1024 + (k-1024));
    float4 a = *(const float4*)s, b = *(const float4*)(s+4);
    f16x8 v = {(f16)a.x,(f16)a.y,(f16)a.z,(f16)a.w,(f16)b.x,(f16)b.y,(f16)b.z,(f16)b.w};
    *(f16x8*)(B1 + (size_t)flat*8) = v;
}

// ---------------- persistent LSTM ----------------
// h packed in A-fragment order: A[parity][kc 128][batch 256][8 halfs]
// Blocks 0..63  : L0 (all-m x 16 j-cols; waves split m; B LDS-chunked, A global)
// Blocks 64..191: L1 (m-quarter x 32 j-cols; waves split n; A LDS-chunked, B global)
// Phase p: L0 computes h0[p] (p<512); L1 computes h1[p-1] (p>=1). 513 barriers.
__global__ void __launch_bounds__(256, 1) lstm_persist(
    const float* __restrict__ seq,  const float* __restrict__ Wih0,
    const float* __restrict__ bih0, const float* __restrict__ bhh0,
    const float* __restrict__ bih1, const float* __restrict__ bhh1,
    const float* __restrict__ linW, const float* __restrict__ linb,
    const f16* __restrict__ B0, const f16* __restrict__ B1,
    f16* __restrict__ A0, f16* __restrict__ A1, float* __restrict__ out,
    int* __restrict__ bar)
{
    __shared__ f16   ldsOp[2][8192];      // 32 KB double-buffered operand chunks
    __shared__ float ldsC[4096];
    __shared__ float ldsX[NBATCH*INP];
    __shared__ float ldsWx[64*INP];
    __shared__ float ldsBias[128];

    const int tid = threadIdx.x, lane = tid & 63, wav = tid >> 6;
    const int quad = lane >> 4, l15 = lane & 15;
    const int blk = blockIdx.x;
    constexpr int ASZ = 128*256*8;        // halfs per parity plane

    if (blk < 64) {
        // ================= L0 =================
        const int j0 = blk*16;
        if (tid < 64) {
            int R = (tid>>4)*1024 + j0 + (tid&15);
            ldsBias[tid] = bih0[R] + bhh0[R];
            #pragma unroll
            for (int i=0;i<INP;++i) ldsWx[tid*INP+i] = Wih0[(size_t)R*INP + i];
        }
        for (int i=tid;i<4096;i+=256) ldsC[i] = 0.f;
        const f16* Bs = B0 + (size_t)blk*(128*64*8);

        for (int p=0;p<=LSEQ;++p){
            if (p < LSEQ){
                for (int i=tid;i<NBATCH*INP;i+=256) ldsX[i] = seq[(size_t)p*NBATCH*INP + i];
                const f16* Ar = A0 + (size_t)((p+1)&1)*ASZ;
                f16*       Aw = A0 + (size_t)(p&1)*ASZ;

                f32x4 acc[4][4];
                #pragma unroll
                for (int a=0;a<4;++a)
                    #pragma unroll
                    for (int b=0;b<4;++b) acc[a][b] = (f32x4){0.f,0.f,0.f,0.f};

                uint4 st[4];
                #pragma unroll
                for (int i=0;i<4;++i) st[i] = *(const uint4*)(Bs + (size_t)(i*256+tid)*8);
                f16x8 a[4];
                #pragma unroll
                for (int mt=0;mt<4;++mt)   // window 0: kc = quad
                    a[mt] = *(const f16x8*)(Ar + ((size_t)quad*256 + wav*64 + mt*16 + l15)*8);

                for (int c=0;c<8;++c){
                    __syncthreads();                       // readers of lds[c&1] done
                    f16* dst = ldsOp[c&1];
                    #pragma unroll
                    for (int i=0;i<4;++i) *(uint4*)(dst + (size_t)(i*256+tid)*8) = st[i];
                    __syncthreads();                       // stores visible
                    if (c < 7){
                        #pragma unroll
                        for (int i=0;i<4;++i)
                            st[i] = *(const uint4*)(Bs + (size_t)(c+1)*8192 + (size_t)(i*256+tid)*8);
                    }
                    const f16* lb = ldsOp[c&1];
                    f16x8 b0[4];
                    #pragma unroll
                    for (int g=0;g<4;++g)
                        b0[g] = *(const f16x8*)(lb + ((size_t)(quad*64) + g*16 + l15)*8);
                    #pragma unroll
                    for (int w=0;w<4;++w){
                        int Wn = c*4 + w + 1; if (Wn > 31) Wn = 31;
                        f16x8 an[4], bn[4];
                        #pragma unroll
                        for (int mt=0;mt<4;++mt)
                            an[mt] = *(const f16x8*)(Ar + ((size_t)(Wn*4+quad)*256 + wav*64 + mt*16 + l15)*8);
                        if (w < 3){
                            #pragma unroll
                            for (int g=0;g<4;++g)
                                bn[g] = *(const f16x8*)(lb + ((size_t)(((w+1)*4+quad)*64) + g*16 + l15)*8);
                        }
                        #pragma unroll
                        for (int mt=0;mt<4;++mt)
                            #pragma unroll
                            for (int g=0;g<4;++g)
                                acc[mt][g] = __builtin_amdgcn_mfma_f32_16x16x32_f16(a[mt], b0[g], acc[mt][g], 0,0,0);
                        #pragma unroll
                        for (int mt=0;mt<4;++mt) a[mt] = an[mt];
                        if (w < 3){
                            #pragma unroll
                            for (int g=0;g<4;++g) b0[g] = bn[g];
                        }
                    }
                }
                // epilogue
                float bs[4], wx[4][INP];
                #pragma unroll
                for (int g=0;g<4;++g){
                    bs[g] = ldsBias[g*16 + l15];
                    #pragma unroll
                    for (int i=0;i<INP;++i) wx[g][i] = ldsWx[(g*16+l15)*INP + i];
                }
                const int kcw = (j0>>3) + (l15>>3);
                #pragma unroll
                for (int mt=0;mt<4;++mt){
                    #pragma unroll
                    for (int r=0;r<4;++r){
                        int m = wav*64 + mt*16 + quad*4 + r;
                        float xv[INP];
                        #pragma unroll
                        for (int i=0;i<INP;++i) xv[i] = ldsX[m*INP + i];
                        float gv[4];
                        #pragma unroll
                        for (int g=0;g<4;++g){
                            float v = acc[mt][g][r] + bs[g];
                            #pragma unroll
                            for (int i=0;i<INP;++i) v += xv[i]*wx[g][i];
                            gv[g] = v;
                        }
                        float I=sigm(gv[0]), F=sigm(gv[1]), G=tanh_f(gv[2]), O=sigm(gv[3]);
                        float cv = ldsC[m*16 + l15];
                        float cn = F*cv + I*G;
                        ldsC[m*16 + l15] = cn;
                        float h = O*tanh_f(cn);
                        Aw[((size_t)kcw*256 + m)*8 + (l15&7)] = (f16)h;
                    }
                }
            }
            grid_barrier(bar);
        }
        // final linear on h1[511] (parity 1)
        {
            int n = blk*4 + wav;
            const f16* hp = A1 + (size_t)ASZ;
            float s = 0.f;
            #pragma unroll
            for (int c2=0;c2<2;++c2){
                int kc = lane*2 + c2;
                f16x8 hv = *(const f16x8*)(hp + ((size_t)kc*256 + n)*8);
                #pragma unroll
                for (int j=0;j<8;++j) s += (float)hv[j] * linW[kc*8 + j];
            }
            #pragma unroll
            for (int m=32;m>=1;m>>=1) s += __shfl_xor(s, m, 64);
            if (lane == 0) out[n] = s + linb[0];
        }
    } else {
        // ================= L1 =================
        const int li = blk - 64, nb = li & 31, mq = li >> 5;
        const int j0 = nb*32;
        if (tid < 128){
            int w = tid>>5, tt = (tid>>4)&1, sub = tid&15;
            int gate = tt*2 + (sub>>3);
            int j = j0 + w*8 + (sub&7);
            int R = gate*1024 + j;
            ldsBias[tid] = bih1[R] + bhh1[R];
        }
        for (int i=tid;i<2048;i+=256) ldsC[i] = 0.f;
        const f16* Bs = B1 + (size_t)nb*(256*128*8);

        for (int p=0;p<=LSEQ;++p){
            if (p >= 1){
                const f16* A0r = A0 + (size_t)((p+1)&1)*ASZ;   // h0[p-1]
                const f16* A1r = A1 + (size_t)(p&1)*ASZ;       // h1[p-2]
                f16*       A1w = A1 + (size_t)((p+1)&1)*ASZ;   // h1[p-1]

                f32x4 acc[4][2];
                #pragma unroll
                for (int a=0;a<4;++a){ acc[a][0]=(f32x4){0,0,0,0}; acc[a][1]=(f32x4){0,0,0,0}; }

                uint4 st[4];
                #pragma unroll
                for (int i=0;i<4;++i){
                    int idx = i*256 + tid, kci = idx>>6, part = idx&63;
                    st[i] = *(const uint4*)(A0r + ((size_t)kci*256 + mq*64 + part)*8);
                }
                f16x8 bf[2];
                #pragma unroll
                for (int t=0;t<2;++t)   // window 0: kc = quad
                    bf[t] = *(const f16x8*)(Bs + ((size_t)quad*128 + wav*32 + t*16 + l15)*8);

                for (int c=0;c<16;++c){
                    __syncthreads();
                    f16* dst = ldsOp[c&1];
                    #pragma unroll
                    for (int i=0;i<4;++i) *(uint4*)(dst + (size_t)(i*256+tid)*8) = st[i];
                    __syncthreads();
                    if (c < 15){
                        const f16* Asrc = (c+1 < 8) ? A0r : A1r;
                        int cb = (c+1 < 8) ? (c+1) : (c+1-8);
                        #pragma unroll
                        for (int i=0;i<4;++i){
                            int idx = i*256 + tid, kci = idx>>6, part = idx&63;
                            st[i] = *(const uint4*)(Asrc + ((size_t)(cb*16+kci)*256 + mq*64 + part)*8);
                        }
                    }
                    const f16* la = ldsOp[c&1];
                    f16x8 af[4];
                    #pragma unroll
                    for (int mt=0;mt<4;++mt)
                        af[mt] = *(const f16x8*)(la + ((size_t)(quad*64) + mt*16 + l15)*8);
                    #pragma unroll
                    for (int w=0;w<4;++w){
                        int Wn = c*4 + w + 1; if (Wn > 63) Wn = 63;
                        f16x8 bn2[2], afn[4];
                        #pragma unroll
                        for (int t=0;t<2;++t)
                            bn2[t] = *(const f16x8*)(Bs + ((size_t)(Wn*4+quad)*128 + wav*32 + t*16 + l15)*8);
                        if (w < 3){
                            #pragma unroll
                            for (int mt=0;mt<4;++mt)
                                afn[mt] = *(const f16x8*)(la + ((size_t)(((w+1)*4+quad)*64) + mt*16 + l15)*8);
                        }
                        #pragma unroll
                        for (int mt=0;mt<4;++mt)
                            #pragma unroll
                            for (int t=0;t<2;++t)
                                acc[mt][t] = __builtin_amdgcn_mfma_f32_16x16x32_f16(af[mt], bf[t], acc[mt][t], 0,0,0);
                        #pragma unroll
                        for (int t=0;t<2;++t) bf[t] = bn2[t];
                        if (w < 3){
                            #pragma unroll
                            for (int mt=0;mt<4;++mt) af[mt] = afn[mt];
                        }
                    }
                }
                // epilogue: lanes l15<8 own (i,g); partners at l15+8 own (f,o)
                int jj = l15 & 7;
                bool lo8 = (l15 < 8);
                float bi = ldsBias[wav*32 + jj],      bff = ldsBias[wav*32 + 8 + jj];
                float bg = ldsBias[wav*32 + 16 + jj], bo  = ldsBias[wav*32 + 24 + jj];
                #pragma unroll
                for (int mt=0;mt<4;++mt){
                    #pragma unroll
                    for (int r=0;r<4;++r){
                        float v0 = acc[mt][0][r], v1 = acc[mt][1][r];
                        float q0 = __shfl_xor(v0, 8, 64);
                        float q1 = __shfl_xor(v1, 8, 64);
                        if (lo8){
                            int ml = mt*16 + quad*4 + r;
                            int m  = mq*64 + ml;
                            float gi=v0+bi, gf=q0+bff, gg=v1+bg, go=q1+bo;
                            float I=sigm(gi), F=sigm(gf), G=tanh_f(gg), O=sigm(go);
                            float cv = ldsC[ml*32 + wav*8 + jj];
                            float cn = F*cv + I*G;
                            ldsC[ml*32 + wav*8 + jj] = cn;
                            float h = O*tanh_f(cn);
                            A1w[((size_t)(nb*4+wav)*256 + m)*8 + jj] = (f16)h;
                        }
                    }
                }
            }
            grid_barrier(bar);
        }
    }
}

extern "C" void kernel_launch(void* const* d_in, const int* in_sizes, int n_in,
                              void* d_out, int out_size, void* d_ws, size_t ws_size,
                              hipStream_t stream)
{
    (void)in_sizes; (void)n_in; (void)out_size; (void)ws_size;
    const float* seq  = (const float*)d_in[0];
    const float* Wih0 = (const float*)d_in[1];
    const float* Whh0 = (const float*)d_in[2];
    const float* bih0 = (const float*)d_in[3];
    const float* bhh0 = (const float*)d_in[4];
    const float* Wih1 = (const float*)d_in[5];
    const float* Whh1 = (const float*)d_in[6];
    const float* bih1 = (const float*)d_in[7];
    const float* bhh1 = (const float*)d_in[8];
    const float* linW = (const float*)d_in[9];
    const float* linb = (const float*)d_in[10];
    float* outp = (float*)d_out;

    char* ws = (char*)d_ws;
    f16* A0p = (f16*)ws;                      // [2][128][256][8] = 1 MB
    f16* A1p = (f16*)(ws + (1<<20));          // 1 MB
    f16* B0p = (f16*)(ws + (2<<20));          // 8 MB
    f16* B1p = (f16*)(ws + (size_t)(10<<20)); // 16 MB
    int* bar = (int*)(ws + (size_t)(26<<20)); // barrier state

    pack_B0<<<2048, 256, 0, stream>>>(Whh0, B0p);
    pack_B1<<<4096, 256, 0, stream>>>(Wih1, Whh1, B1p);
    hipMemsetAsync(ws, 0, 2<<20, stream);     // zero h parity buffers
    hipMemsetAsync(bar, 0, 256, stream);      // zero barrier state

    lstm_persist<<<dim3(NBLK), dim3(256), 0, stream>>>(
        seq, Wih0, bih0, bhh0, bih1, bhh1, linW, linb,
        B0p, B1p, A0p, A1p, outp, bar);
}

// Round 5
// 19397.980 us; speedup vs baseline: 1.8563x; 1.8563x over previous
//
#include <hip/hip_runtime.h>
#include <cstdint>
#include <cstddef>

#define LSEQ 512
#define NBATCH 256
#define INP 6
#define NBLK 192

typedef _Float16 f16;
typedef f16 f16x8 __attribute__((ext_vector_type(8)));
typedef float f32x4 __attribute__((ext_vector_type(4)));
typedef unsigned long long u64t;

static __device__ __forceinline__ float sigm(float x){ return 1.f/(1.f+__expf(-x)); }
static __device__ __forceinline__ float tanh_f(float x){
    x = fminf(fmaxf(x,-15.f),15.f);
    float t = __expf(-2.f*x);
    return (1.f-t)/(1.f+t);
}
// agent-scope cache-bypassing load: always coherent with IC (no L2 inv needed)
static __device__ __forceinline__ u64t hload(const u64t* p){
    return __hip_atomic_load(p, __ATOMIC_RELAXED, __HIP_MEMORY_SCOPE_AGENT);
}
union U64F16 { u64t q[2]; f16x8 v; };

// Grid barrier WITHOUT reader-side L2 invalidate. Writer: release fence
// (wbL2 only) -> relaxed arrive. Readers spin relaxed; h is read via hload
// (IC-coherent) so no acquire-invalidate is required; weights are read-only
// so their L2 copies stay valid across phases.
static __device__ __forceinline__ void grid_barrier(int* bar){
    __syncthreads();
    if (threadIdx.x == 0){
        __builtin_amdgcn_fence(__ATOMIC_RELEASE, "agent");
        int g = __hip_atomic_load(&bar[16], __ATOMIC_RELAXED, __HIP_MEMORY_SCOPE_AGENT);
        int old = __hip_atomic_fetch_add(&bar[0], 1, __ATOMIC_RELAXED, __HIP_MEMORY_SCOPE_AGENT);
        if (old == NBLK - 1){
            __hip_atomic_store(&bar[0], 0, __ATOMIC_RELAXED, __HIP_MEMORY_SCOPE_AGENT);
            __hip_atomic_store(&bar[16], g + 1, __ATOMIC_RELEASE, __HIP_MEMORY_SCOPE_AGENT);
        } else {
            while (__hip_atomic_load(&bar[16], __ATOMIC_RELAXED, __HIP_MEMORY_SCOPE_AGENT) == g)
                __builtin_amdgcn_s_sleep(1);
        }
    }
    __syncthreads();
}

// ---------------- weight packing (once per call) ----------------
// B0: [kc8 128][r 64][8], r = g*16+jl -> row g*1024 + nb*16 + jl ; per nb-slice
__global__ void pack_B0(const float* __restrict__ Whh0, f16* __restrict__ B0){
    int flat = blockIdx.x*256 + threadIdx.x;          // 524288
    int r = flat & 63, kc = (flat>>6)&127, nb = flat>>13;
    int g = r>>4, jl = r&15;
    const float* s = Whh0 + (size_t)(g*1024 + nb*16 + jl)*1024 + kc*8;
    float4 a = *(const float4*)s, b = *(const float4*)(s+4);
    f16x8 v = {(f16)a.x,(f16)a.y,(f16)a.z,(f16)a.w,(f16)b.x,(f16)b.y,(f16)b.z,(f16)b.w};
    *(f16x8*)(B0 + (size_t)flat*8) = v;
}
// B1: [nb 32][kc 256][r 128][8], r = w*32+tt*16+sub, gate=tt*2+(sub>>3), j=nb*32+w*8+(sub&7)
__global__ void pack_B1(const float* __restrict__ Wih1, const float* __restrict__ Whh1,
                        f16* __restrict__ B1){
    int flat = blockIdx.x*256 + threadIdx.x;          // 1048576
    int r = flat & 127, kc = (flat>>7)&255, nb = flat>>15;
    int w = r>>5, tt = (r>>4)&1, sub = r&15;
    int gate = tt*2 + (sub>>3);
    int j = nb*32 + w*8 + (sub&7);
    int R = gate*1024 + j;
    int k = kc*8;
    const float* s = (k<1024) ? (Wih1 + (size_t)R*1024 + k)
                              : (Whh1 + (size_t)R*1024 + (k-1024));
    float4 a = *(const float4*)s, b = *(const float4*)(s+4);
    f16x8 v = {(f16)a.x,(f16)a.y,(f16)a.z,(f16)a.w,(f16)b.x,(f16)b.y,(f16)b.z,(f16)b.w};
    *(f16x8*)(B1 + (size_t)flat*8) = v;
}

// ---------------- persistent LSTM ----------------
// h packed A-layout: A[parity][kc8 128][m 256][8 halfs]
// Blocks 0..63  : L0. 16 j-cols, all m; waves split m (64 rows).
//                 B LDS-chunked (8x16KB db, L2-hot), A register-rolled depth-4 hloads.
// Blocks 64..191: L1. mq(64 rows) x 32 j-cols; waves split n (8 j-cols).
//                 A LDS-chunked via hload bursts; B direct depth-4 (L2-hot).
__global__ void __launch_bounds__(256, 1) lstm_persist(
    const float* __restrict__ seq,  const float* __restrict__ Wih0,
    const float* __restrict__ bih0, const float* __restrict__ bhh0,
    const float* __restrict__ bih1, const float* __restrict__ bhh1,
    const float* __restrict__ linW, const float* __restrict__ linb,
    const f16* __restrict__ B0, const f16* __restrict__ B1,
    f16* __restrict__ A0, f16* __restrict__ A1, float* __restrict__ out,
    int* __restrict__ bar)
{
    __shared__ char ldsraw[41216] __attribute__((aligned(16)));

    const int tid = threadIdx.x, lane = tid & 63, wav = tid >> 6;
    const int quad = lane >> 4, l15 = lane & 15;
    const int blk = blockIdx.x;
    constexpr int ASZ = 128*256*8;        // halfs per parity plane

    if (blk < 64) {
        // ================= L0 =================
        f16*   ldsB   = (f16*)ldsraw;                       // 2 x 8192 halfs
        float* ldsX   = (float*)(ldsraw + 32768);           // 1536 f
        float* ldsWx  = (float*)(ldsraw + 32768 + 6144);    // 384 f
        float* ldsBias= (float*)(ldsraw + 32768 + 6144 + 1536); // 64 f

        const int j0 = blk*16;
        if (tid < 64) {
            int R = (tid>>4)*1024 + j0 + (tid&15);
            ldsBias[tid] = bih0[R] + bhh0[R];
            #pragma unroll
            for (int i=0;i<INP;++i) ldsWx[tid*INP+i] = Wih0[(size_t)R*INP + i];
        }
        const uint4* Bs4 = (const uint4*)(B0 + (size_t)blk*(128*64*8));
        float creg[4][4];
        #pragma unroll
        for (int a=0;a<4;++a)
            #pragma unroll
            for (int b=0;b<4;++b) creg[a][b] = 0.f;

        for (int p=0;p<=LSEQ;++p){
            if (p < LSEQ){
                for (int i=tid;i<NBATCH*INP;i+=256) ldsX[i] = seq[(size_t)p*NBATCH*INP + i];
                const u64t* Ar64 = (const u64t*)(A0 + (size_t)((p+1)&1)*ASZ);
                f16*        Aw   = A0 + (size_t)(p&1)*ASZ;

                f32x4 acc[4][4];
                #pragma unroll
                for (int a=0;a<4;++a)
                    #pragma unroll
                    for (int b=0;b<4;++b) acc[a][b] = (f32x4){0.f,0.f,0.f,0.f};

                uint4 sb[4];
                #pragma unroll
                for (int i=0;i<4;++i) sb[i] = Bs4[i*256 + tid];
                U64F16 ar[4][4];                         // depth-4 window roll
                #pragma unroll
                for (int d=0; d<4; ++d)
                    #pragma unroll
                    for (int mt=0;mt<4;++mt){
                        size_t base = ((size_t)(d*4+quad)*256 + wav*64 + mt*16 + l15)*2;
                        ar[d][mt].q[0] = hload(Ar64 + base);
                        ar[d][mt].q[1] = hload(Ar64 + base + 1);
                    }

                for (int c=0;c<8;++c){
                    __syncthreads();
                    f16* dst = ldsB + (c&1)*8192;
                    #pragma unroll
                    for (int i=0;i<4;++i) ((uint4*)dst)[i*256 + tid] = sb[i];
                    __syncthreads();
                    if (c < 7){
                        #pragma unroll
                        for (int i=0;i<4;++i) sb[i] = Bs4[(size_t)(c+1)*1024 + i*256 + tid];
                    }
                    const f16* lb = ldsB + (c&1)*8192;
                    #pragma unroll
                    for (int w=0;w<4;++w){
                        const int n = c*4 + w;
                        f16x8 bf[4];
                        #pragma unroll
                        for (int g=0;g<4;++g)
                            bf[g] = *(const f16x8*)(lb + ((size_t)(w*4+quad)*64 + g*16 + l15)*8);
                        #pragma unroll
                        for (int mt=0;mt<4;++mt)
                            #pragma unroll
                            for (int g=0;g<4;++g)
                                acc[mt][g] = __builtin_amdgcn_mfma_f32_16x16x32_f16(ar[w][mt].v, bf[g], acc[mt][g], 0,0,0);
                        if (c < 7){                      // refill window n+4 into slot w
                            #pragma unroll
                            for (int mt=0;mt<4;++mt){
                                size_t base = ((size_t)((n+4)*4+quad)*256 + wav*64 + mt*16 + l15)*2;
                                ar[w][mt].q[0] = hload(Ar64 + base);
                                ar[w][mt].q[1] = hload(Ar64 + base + 1);
                            }
                        }
                    }
                }
                // epilogue
                float bs[4], wx[4][INP];
                #pragma unroll
                for (int g=0;g<4;++g){
                    bs[g] = ldsBias[g*16 + l15];
                    #pragma unroll
                    for (int i=0;i<INP;++i) wx[g][i] = ldsWx[(g*16+l15)*INP + i];
                }
                const int kcw = (j0>>3) + (l15>>3);
                #pragma unroll
                for (int mt=0;mt<4;++mt){
                    #pragma unroll
                    for (int r=0;r<4;++r){
                        int m = wav*64 + mt*16 + quad*4 + r;
                        float xv[INP];
                        #pragma unroll
                        for (int i=0;i<INP;++i) xv[i] = ldsX[m*INP + i];
                        float gv[4];
                        #pragma unroll
                        for (int g=0;g<4;++g){
                            float v = acc[mt][g][r] + bs[g];
                            #pragma unroll
                            for (int i=0;i<INP;++i) v += xv[i]*wx[g][i];
                            gv[g] = v;
                        }
                        float I=sigm(gv[0]), F=sigm(gv[1]), G=tanh_f(gv[2]), O=sigm(gv[3]);
                        float cn = F*creg[mt][r] + I*G;
                        creg[mt][r] = cn;
                        float h = O*tanh_f(cn);
                        Aw[((size_t)kcw*256 + m)*8 + (l15&7)] = (f16)h;
                    }
                }
            }
            grid_barrier(bar);
        }
        // final linear on h1[511] (parity 1)
        {
            int n = blk*4 + wav;
            const u64t* hp = (const u64t*)(A1 + (size_t)ASZ);
            float s = 0.f;
            #pragma unroll
            for (int c2=0;c2<2;++c2){
                int kc = lane*2 + c2;
                U64F16 hv;
                size_t base = ((size_t)kc*256 + n)*2;
                hv.q[0] = hload(hp + base);
                hv.q[1] = hload(hp + base + 1);
                #pragma unroll
                for (int j=0;j<8;++j) s += (float)hv.v[j] * linW[kc*8 + j];
            }
            #pragma unroll
            for (int m=32;m>=1;m>>=1) s += __shfl_xor(s, m, 64);
            if (lane == 0) out[n] = s + linb[0];
        }
    } else {
        // ================= L1 =================
        f16*   ldsA    = (f16*)ldsraw;                      // 2 x 8192 halfs
        float* ldsBias = (float*)(ldsraw + 32768);          // 128 f

        const int li = blk - 64, nb = li & 31, mq = li >> 5;
        const int j0 = nb*32;
        if (tid < 128){
            int w = tid>>5, tt = (tid>>4)&1, sub = tid&15;
            int gate = tt*2 + (sub>>3);
            int j = j0 + w*8 + (sub&7);
            int R = gate*1024 + j;
            ldsBias[tid] = bih1[R] + bhh1[R];
        }
        const f16* Bs = B1 + (size_t)nb*(256*128*8);
        float creg[4][4];
        #pragma unroll
        for (int a=0;a<4;++a)
            #pragma unroll
            for (int b=0;b<4;++b) creg[a][b] = 0.f;

        for (int p=0;p<=LSEQ;++p){
            if (p >= 1){
                const u64t* A0r64 = (const u64t*)(A0 + (size_t)((p+1)&1)*ASZ); // h0[p-1]
                const u64t* A1r64 = (const u64t*)(A1 + (size_t)(p&1)*ASZ);     // h1[p-2]
                f16*        A1w   = A1 + (size_t)((p+1)&1)*ASZ;                // h1[p-1]

                f32x4 acc[4][2];
                #pragma unroll
                for (int a=0;a<4;++a){ acc[a][0]=(f32x4){0,0,0,0}; acc[a][1]=(f32x4){0,0,0,0}; }

                u64t st[8];
                #pragma unroll
                for (int i=0;i<8;++i){
                    int idx = i*256 + tid;
                    int u = idx & 1, m = (idx>>1) & 63, kc8 = idx>>7;
                    st[i] = hload(A0r64 + ((size_t)kc8*256 + mq*64 + m)*2 + u);
                }
                f16x8 bq[4][2];                          // depth-4 B window roll
                #pragma unroll
                for (int d=0; d<4; ++d)
                    #pragma unroll
                    for (int t=0;t<2;++t)
                        bq[d][t] = *(const f16x8*)(Bs + ((size_t)(d*4+quad)*128 + wav*32 + t*16 + l15)*8);

                for (int c=0;c<16;++c){
                    __syncthreads();
                    u64t* dst = (u64t*)(ldsA + (c&1)*8192);
                    #pragma unroll
                    for (int i=0;i<8;++i) dst[i*256 + tid] = st[i];
                    __syncthreads();
                    if (c < 15){
                        int cb = c + 1;
                        const u64t* src = (cb < 8) ? A0r64 : A1r64;
                        int cb2 = (cb < 8) ? cb : cb - 8;
                        #pragma unroll
                        for (int i=0;i<8;++i){
                            int idx = i*256 + tid;
                            int u = idx & 1, m = (idx>>1) & 63, kc8 = idx>>7;
                            st[i] = hload(src + ((size_t)(cb2*16 + kc8)*256 + mq*64 + m)*2 + u);
                        }
                    }
                    const f16* la = ldsA + (c&1)*8192;
                    #pragma unroll
                    for (int w=0;w<4;++w){
                        const int n = c*4 + w;
                        f16x8 af[4];
                        #pragma unroll
                        for (int mt=0;mt<4;++mt)
                            af[mt] = *(const f16x8*)(la + ((size_t)(w*4+quad)*64 + mt*16 + l15)*8);
                        #pragma unroll
                        for (int mt=0;mt<4;++mt)
                            #pragma unroll
                            for (int t=0;t<2;++t)
                                acc[mt][t] = __builtin_amdgcn_mfma_f32_16x16x32_f16(af[mt], bq[w][t], acc[mt][t], 0,0,0);
                        if (c < 15){                     // refill window n+4 into slot w
                            #pragma unroll
                            for (int t=0;t<2;++t)
                                bq[w][t] = *(const f16x8*)(Bs + ((size_t)((n+4)*4+quad)*128 + wav*32 + t*16 + l15)*8);
                        }
                    }
                }
                // epilogue: lanes l15<8 own (i,g); partners at l15+8 own (f,o)
                int jj = l15 & 7;
                bool lo8 = (l15 < 8);
                float bi = ldsBias[wav*32 + jj],      bff = ldsBias[wav*32 + 8 + jj];
                float bg = ldsBias[wav*32 + 16 + jj], bo  = ldsBias[wav*32 + 24 + jj];
                #pragma unroll
                for (int mt=0;mt<4;++mt){
                    #pragma unroll
                    for (int r=0;r<4;++r){
                        float v0 = acc[mt][0][r], v1 = acc[mt][1][r];
                        float q0 = __shfl_xor(v0, 8, 64);
                        float q1 = __shfl_xor(v1, 8, 64);
                        if (lo8){
                            int m = mq*64 + mt*16 + quad*4 + r;
                            float gi=v0+bi, gf=q0+bff, gg=v1+bg, go=q1+bo;
                            float I=sigm(gi), F=sigm(gf), G=tanh_f(gg), O=sigm(go);
                            float cn = F*creg[mt][r] + I*G;
                            creg[mt][r] = cn;
                            float h = O*tanh_f(cn);
                            A1w[((size_t)(nb*4+wav)*256 + m)*8 + jj] = (f16)h;
                        }
                    }
                }
            }
            grid_barrier(bar);
        }
    }
}

extern "C" void kernel_launch(void* const* d_in, const int* in_sizes, int n_in,
                              void* d_out, int out_size, void* d_ws, size_t ws_size,
                              hipStream_t stream)
{
    (void)in_sizes; (void)n_in; (void)out_size; (void)ws_size;
    const float* seq  = (const float*)d_in[0];
    const float* Wih0 = (const float*)d_in[1];
    const float* Whh0 = (const float*)d_in[2];
    const float* bih0 = (const float*)d_in[3];
    const float* bhh0 = (const float*)d_in[4];
    const float* Wih1 = (const float*)d_in[5];
    const float* Whh1 = (const float*)d_in[6];
    const float* bih1 = (const float*)d_in[7];
    const float* bhh1 = (const float*)d_in[8];
    const float* linW = (const float*)d_in[9];
    const float* linb = (const float*)d_in[10];
    float* outp = (float*)d_out;

    char* ws = (char*)d_ws;
    f16* A0p = (f16*)ws;                      // [2][128][256][8] = 1 MB
    f16* A1p = (f16*)(ws + (1<<20));          // 1 MB
    f16* B0p = (f16*)(ws + (2<<20));          // 8 MB
    f16* B1p = (f16*)(ws + (size_t)(10<<20)); // 16 MB
    int* bar = (int*)(ws + (size_t)(26<<20)); // barrier state

    pack_B0<<<2048, 256, 0, stream>>>(Whh0, B0p);
    pack_B1<<<4096, 256, 0, stream>>>(Wih1, Whh1, B1p);
    hipMemsetAsync(ws, 0, 2<<20, stream);     // zero h parity buffers
    hipMemsetAsync(bar, 0, 256, stream);      // zero barrier state

    lstm_persist<<<dim3(NBLK), dim3(256), 0, stream>>>(
        seq, Wih0, bih0, bhh0, bih1, bhh1, linW, linb,
        B0p, B1p, A0p, A1p, outp, bar);
}